// Round 1
// baseline (138.209 us; speedup 1.0000x reference)
//
#include <hip/hip_runtime.h>
#include <hip/hip_bf16.h>

// Problem constants (match reference)
#define B 8
#define S 2048
#define N 512
#define D 1024
#define MAX_W 32
#define MASK_FILL -1000.0f

// ---------------------------------------------------------------------------
// Kernel 1: logits[b,s] = dot(seq[b,s,:], att_w) + att_b
// One 64-lane wave per row; each lane handles 4 float4 (16 floats) -> 1024.
// ---------------------------------------------------------------------------
__global__ __launch_bounds__(256) void logits_kernel(
    const float* __restrict__ seq,
    const float* __restrict__ att_w,
    const float* __restrict__ att_b,
    float* __restrict__ logits)
{
    const int row  = blockIdx.x * 4 + (threadIdx.x >> 6);   // 4 waves / block
    const int lane = threadIdx.x & 63;

    const float4* rp = (const float4*)(seq + (size_t)row * D);
    const float4* wp = (const float4*)att_w;

    float acc = 0.0f;
#pragma unroll
    for (int k = 0; k < 4; ++k) {
        const float4 a = rp[lane + 64 * k];
        const float4 w = wp[lane + 64 * k];
        acc += a.x * w.x + a.y * w.y + a.z * w.z + a.w * w.w;
    }

    // wave-64 reduction
#pragma unroll
    for (int off = 32; off > 0; off >>= 1)
        acc += __shfl_down(acc, off);

    if (lane == 0)
        logits[row] = acc + att_b[0];
}

// ---------------------------------------------------------------------------
// Kernel 2: per-span masked softmax over gathered logits + weighted pooling.
// One block (256 threads) per span. Lanes 0..31 compute softmax into LDS;
// then each thread owns one float4 column slice of D.
// Masked entries: expf(-1000 - m) == 0.0f in fp32 (identical to the JAX
// reference's softmax result), so the pooling loop runs only over the
// width+1 valid positions — bit-identical output, half the gather traffic.
// ---------------------------------------------------------------------------
__global__ __launch_bounds__(256) void pool_kernel(
    const float* __restrict__ seq,
    const int*   __restrict__ spans,
    const float* __restrict__ logits,
    float* __restrict__ out)
{
    const int span = blockIdx.x;           // 0 .. B*N-1
    const int b    = span / N;

    const int start = spans[2 * span + 0];
    const int end   = spans[2 * span + 1]; // inclusive
    const int width = end - start;         // valid entries = width + 1

    __shared__ float s_attn[MAX_W];
    __shared__ int   s_idx[MAX_W];

    const int tid = threadIdx.x;

    if (tid < MAX_W) {
        const int w   = tid;
        const int raw = end - w;
        const bool valid = (w <= width) && (raw >= 0);
        const int idx = raw > 0 ? raw : 0;
        const float l = valid ? logits[b * S + idx] : MASK_FILL;

        // max over the 32 lanes (width-32 shuffles within wave 0)
        float m = l;
#pragma unroll
        for (int off = 16; off > 0; off >>= 1)
            m = fmaxf(m, __shfl_down(m, off, 32));
        m = __shfl(m, 0, 32);

        const float p = __expf(l - m);

        float sum = p;
#pragma unroll
        for (int off = 16; off > 0; off >>= 1)
            sum += __shfl_down(sum, off, 32);
        sum = __shfl(sum, 0, 32);

        s_attn[w] = p / sum;
        s_idx[w]  = idx;
    }
    __syncthreads();

    // weighted sum over valid span positions; thread tid owns float4 #tid
    const size_t seq_base = (size_t)b * S;
    float4 acc = make_float4(0.f, 0.f, 0.f, 0.f);

    const int cnt = width + 1;             // wave-uniform per block
    for (int w = 0; w < cnt; ++w) {
        const float a = s_attn[w];
        const float4 v =
            ((const float4*)(seq + (seq_base + (size_t)s_idx[w]) * D))[tid];
        acc.x += a * v.x;
        acc.y += a * v.y;
        acc.z += a * v.z;
        acc.w += a * v.w;
    }

    ((float4*)(out + (size_t)span * D))[tid] = acc;
}

// ---------------------------------------------------------------------------
extern "C" void kernel_launch(void* const* d_in, const int* in_sizes, int n_in,
                              void* d_out, int out_size, void* d_ws, size_t ws_size,
                              hipStream_t stream)
{
    const float* seq    = (const float*)d_in[0];  // (B,S,D) f32
    const int*   spans  = (const int*)  d_in[1];  // (B,N,2) i32
    const float* att_w  = (const float*)d_in[2];  // (D,1)   f32
    const float* att_b  = (const float*)d_in[3];  // (1,)    f32

    float* out    = (float*)d_out;                // (B,N,D) f32
    float* logits = (float*)d_ws;                 // (B,S)   f32 scratch

    logits_kernel<<<(B * S) / 4, 256, 0, stream>>>(seq, att_w, att_b, logits);
    pool_kernel<<<B * N, 256, 0, stream>>>(seq, spans, logits, out);
}

// Round 3
// 123.319 us; speedup vs baseline: 1.1207x; 1.1207x over previous
//
#include <hip/hip_runtime.h>
#include <hip/hip_bf16.h>

// Problem constants (match reference)
#define B 8
#define S 2048
#define N 512
#define D 1024
#define MAX_W 32
#define MASK_FILL -1000.0f

// native clang vector type — required by __builtin_nontemporal_store
typedef float vfloat4 __attribute__((ext_vector_type(4)));

// ---------------------------------------------------------------------------
// Kernel 1: logits[b,s] = dot(seq[b,s,:], att_w) + att_b
// One 64-lane wave per row; each lane handles 4 float4 (16 floats) -> 1024.
// HBM-bound: reads 64 MiB of seq once (also warms L3 for the pool kernel).
// ---------------------------------------------------------------------------
__global__ __launch_bounds__(256) void logits_kernel(
    const float* __restrict__ seq,
    const float* __restrict__ att_w,
    const float* __restrict__ att_b,
    float* __restrict__ logits)
{
    const int row  = blockIdx.x * 4 + (threadIdx.x >> 6);   // 4 waves / block
    const int lane = threadIdx.x & 63;

    const float4* rp = (const float4*)(seq + (size_t)row * D);
    const float4* wp = (const float4*)att_w;

    float acc = 0.0f;
#pragma unroll
    for (int k = 0; k < 4; ++k) {
        const float4 a = rp[lane + 64 * k];
        const float4 w = wp[lane + 64 * k];
        acc += a.x * w.x + a.y * w.y + a.z * w.z + a.w * w.w;
    }

    // wave-64 reduction
#pragma unroll
    for (int off = 32; off > 0; off >>= 1)
        acc += __shfl_down(acc, off);

    if (lane == 0)
        logits[row] = acc + att_b[0];
}

// ---------------------------------------------------------------------------
// Kernel 2: per-span masked softmax + weighted pooling.
// One block (256 threads) per span; thread tid owns float4 column slice #tid.
//
// XCD swizzle: blockIdx & 7 selects the batch. Workgroups dispatch
// round-robin over the 8 XCDs, so each XCD's 4 MiB L2 only ever sees its
// own batch's 8 MiB seq slice (instead of all 64 MiB) -> L2 locality.
// (Heuristic only: a different mapping just permutes span order —
// correctness unaffected.)
//
// Softmax-skip: masked entries have weight exactly 0 (expf(-1000-m)==0 in
// fp32, identical to the reference), s_idx is clamped to a valid row, so
// looping w in [0, cnt4) with cnt4 = roundup4(width+1) is bit-identical to
// the reference while enabling a 4-deep independent-load pipeline.
// ---------------------------------------------------------------------------
__global__ __launch_bounds__(256) void pool_kernel(
    const float* __restrict__ seq,
    const int*   __restrict__ spans,
    const float* __restrict__ logits,
    float* __restrict__ out)
{
    const int b    = blockIdx.x & 7;        // batch -> XCD affinity
    const int n    = blockIdx.x >> 3;       // span within batch
    const int span = b * N + n;

    const int start = spans[2 * span + 0];
    const int end   = spans[2 * span + 1];  // inclusive
    const int width = end - start;          // valid entries = width + 1

    __shared__ float s_attn[MAX_W];
    __shared__ int   s_idx[MAX_W];

    const int tid = threadIdx.x;

    if (tid < MAX_W) {
        const int w   = tid;
        const int raw = end - w;
        const bool valid = (w <= width) && (raw >= 0);
        const int idx = raw > 0 ? raw : 0;
        const float l = valid ? logits[b * S + idx] : MASK_FILL;

        float m = l;
#pragma unroll
        for (int off = 16; off > 0; off >>= 1)
            m = fmaxf(m, __shfl_down(m, off, 32));
        m = __shfl(m, 0, 32);

        const float p = __expf(l - m);

        float sum = p;
#pragma unroll
        for (int off = 16; off > 0; off >>= 1)
            sum += __shfl_down(sum, off, 32);
        sum = __shfl(sum, 0, 32);

        s_attn[w] = p / sum;                // exactly 0 for masked entries
        s_idx[w]  = idx;
    }
    __syncthreads();

    const float* sb = seq + (size_t)b * S * D;
    float4 acc = make_float4(0.f, 0.f, 0.f, 0.f);

    const int cnt  = width + 1;             // wave-uniform per block
    const int cnt4 = (cnt + 3) & ~3;        // <= MAX_W

    for (int w = 0; w < cnt4; w += 4) {
        const float a0 = s_attn[w + 0];
        const float a1 = s_attn[w + 1];
        const float a2 = s_attn[w + 2];
        const float a3 = s_attn[w + 3];
        const int   i0 = s_idx[w + 0];
        const int   i1 = s_idx[w + 1];
        const int   i2 = s_idx[w + 2];
        const int   i3 = s_idx[w + 3];

        const float4 v0 = ((const float4*)(sb + (size_t)i0 * D))[tid];
        const float4 v1 = ((const float4*)(sb + (size_t)i1 * D))[tid];
        const float4 v2 = ((const float4*)(sb + (size_t)i2 * D))[tid];
        const float4 v3 = ((const float4*)(sb + (size_t)i3 * D))[tid];

        acc.x += a0 * v0.x + a1 * v1.x + a2 * v2.x + a3 * v3.x;
        acc.y += a0 * v0.y + a1 * v1.y + a2 * v2.y + a3 * v3.y;
        acc.z += a0 * v0.z + a1 * v1.z + a2 * v2.z + a3 * v3.z;
        acc.w += a0 * v0.w + a1 * v1.w + a2 * v2.w + a3 * v3.w;
    }

    // streaming output: non-temporal store, keep L2 for seq
    vfloat4 vacc;
    vacc.x = acc.x; vacc.y = acc.y; vacc.z = acc.z; vacc.w = acc.w;
    vfloat4* op = ((vfloat4*)(out + (size_t)span * D)) + tid;
    __builtin_nontemporal_store(vacc, op);
}

// ---------------------------------------------------------------------------
extern "C" void kernel_launch(void* const* d_in, const int* in_sizes, int n_in,
                              void* d_out, int out_size, void* d_ws, size_t ws_size,
                              hipStream_t stream)
{
    const float* seq    = (const float*)d_in[0];  // (B,S,D) f32
    const int*   spans  = (const int*)  d_in[1];  // (B,N,2) i32
    const float* att_w  = (const float*)d_in[2];  // (D,1)   f32
    const float* att_b  = (const float*)d_in[3];  // (1,)    f32

    float* out    = (float*)d_out;                // (B,N,D) f32
    float* logits = (float*)d_ws;                 // (B,S)   f32 scratch

    logits_kernel<<<(B * S) / 4, 256, 0, stream>>>(seq, att_w, att_b, logits);
    pool_kernel<<<B * N, 256, 0, stream>>>(seq, spans, logits, out);
}